// Round 7
// baseline (174.470 us; speedup 1.0000x reference)
//
#include <hip/hip_runtime.h>

#define TEMP    0.5f
#define LOG2E   1.4426950408889634f
#define C2      (LOG2E / TEMP)        /* t = dot * C2 */
#define SQC2    1.6986436f            /* sqrt(C2): inputs pre-scaled so MFMA dot = t */
#define MSHIFT  160.0f                /* fixed base-2 softmax shift */
#define LN2     0.6931471805599453f
#define NROWS   16384
#define BHALF   8192
#define DDIM    128
#define PREPB   2048                  /* k_prep blocks = 524288/256 */
#define MAINB   512                   /* k_main blocks */

typedef __bf16 bf16x8 __attribute__((ext_vector_type(8)));
typedef float  f32x16 __attribute__((ext_vector_type(16)));
typedef float  f32x2  __attribute__((ext_vector_type(2)));

__device__ __forceinline__ float fexp2(float x) {
#if __has_builtin(__builtin_amdgcn_exp2f)
  return __builtin_amdgcn_exp2f(x);
#else
  return exp2f(x);
#endif
}

__device__ __forceinline__ unsigned short f2bf(float f) {
  unsigned int u = __float_as_uint(f);
  unsigned int r = (u + 0x7FFFu + ((u >> 16) & 1u)) >> 16;  // RNE
  return (unsigned short)r;
}

// ---------------------------------------------------------------------------
// zbF frag-major layout: for row r, k-index k:
//   g = r/32, lo = r%32, khi = k/8, j = k%8
//   short index = g*4096 + khi*256 + lo*8 + j
// A wave's frag load (fixed ks): 64 lanes read a contiguous 1KB block.
// Values are pre-scaled by SQC2, so an MFMA dot directly yields t = dot/T*log2e.
// ---------------------------------------------------------------------------

// k_prep: cast concat(z_i,z_j)*SQC2 fp32->bf16 into frag-major zbF; per-block
// partial dot(z_i,z_j) (UNscaled, exact fp32) -> Pp[block]; zero S and cnt.
__global__ void k_prep(const float* __restrict__ zi, const float* __restrict__ zj,
                       unsigned short* __restrict__ zbF,
                       float* __restrict__ S, float* __restrict__ Pp,
                       unsigned int* __restrict__ cnt) {
  const int t   = blockIdx.x * 256 + threadIdx.x;   // 0..524287 float4 groups
  const int row = t >> 5;                           // 32 float4 per 128-elt row
  const int k0  = (t & 31) * 4;
  const float* src = (row < BHALF) ? (zi + (size_t)row * DDIM)
                                   : (zj + (size_t)(row - BHALF) * DDIM);
  float4 v = *reinterpret_cast<const float4*>(src + k0);

  const int g = row >> 5, lo = row & 31, khi = k0 >> 3, j0 = k0 & 7;
  ushort4 o;
  o.x = f2bf(v.x * SQC2); o.y = f2bf(v.y * SQC2);
  o.z = f2bf(v.z * SQC2); o.w = f2bf(v.w * SQC2);
  *reinterpret_cast<ushort4*>(zbF + (size_t)g * 4096 + khi * 256 + lo * 8 + j0) = o;

  float dot = 0.f;
  if (row < BHALF) {
    float4 w = *reinterpret_cast<const float4*>(zj + (size_t)row * DDIM + k0);
    dot = fmaf(v.x, w.x, fmaf(v.y, w.y, fmaf(v.z, w.z, v.w * w.w)));
  }
#pragma unroll
  for (int m = 32; m >= 1; m >>= 1) dot += __shfl_xor(dot, m, 64);
  __shared__ float red[4];
  if ((threadIdx.x & 63) == 0) red[threadIdx.x >> 6] = dot;
  __syncthreads();
  if (threadIdx.x == 0) Pp[blockIdx.x] = red[0] + red[1] + red[2] + red[3];

  if (t < NROWS) S[t] = 0.f;
  if (t == 0) cnt[0] = 0u;              // completion counter for fused fin
}

// ---------------------------------------------------------------------------
// k_main: wave holds 128 persistent rows as MFMA *B* operand (lane-indexed in
// C/D -> scalar row sums). Streams 32-col tiles as the A operand, coalesced
// frag loads from frag-major zbF. Single-buffer pipelined reload under the
// exp section. No LDS/barriers in the hot loop.
//
// Round-7 deltas vs the 73.5us r4 kernel (structure frozen — EVERY attempt to
// interleave exp into the MFMA chains spilled (r1/r2/r5: WRITE_SIZE 1->19-162MB),
// and TLP/thin-wave/sleep/setprio variants were neutral or worse (r4/r6):
//  * C-operand kC = -MSHIFT (reg-neutral: replaces the all-zero kZ) + SQC2
//    pre-scale in k_prep  =>  exp section is exp2 + pk_add only (no pk_fma).
//  * k_fin fused in as a last-block epilogue (fence + device-scope counter):
//    one dispatch fewer.
// ---------------------------------------------------------------------------
template <bool MASK>
__device__ __forceinline__ void expAcc(const f32x16& acc, f32x2& s, int d, int hi) {
#pragma unroll
  for (int k = 0; k < 8; ++k) {
    f32x2 e;
    e.x = fexp2(acc[2 * k]);
    e.y = fexp2(acc[2 * k + 1]);
    if (MASK) {
      const int r0 = 2 * k, r1 = 2 * k + 1;
      if (((r0 & 3) + 8 * (r0 >> 2) + 4 * hi) == d) e.x = 0.f;  // C/D reg map
      if (((r1 & 3) + 8 * (r1 >> 2) + 4 * hi) == d) e.y = 0.f;
    }
    s += e;                                                     // v_pk_add_f32
  }
}

#define MFMA_ __builtin_amdgcn_mfma_f32_32x32x16_bf16

__global__ __launch_bounds__(256, 2)
void k_main(const unsigned short* __restrict__ zbF, float* __restrict__ S,
            const float* __restrict__ Pp, unsigned int* __restrict__ cnt,
            float* __restrict__ out) {
  const int wave = threadIdx.x >> 6;
  const int lane = threadIdx.x & 63;
  const int lo = lane & 31;
  const int hi = lane >> 5;
  const int rb = blockIdx.x & 31;       // 32 row blocks of 512 rows
  const int cc = blockIdx.x >> 5;       // 16 col chunks of 1024 cols
  const int row0w = rb * 512 + wave * 128;

  // persistent row frags (B operand): 4 row-tiles x 8 k-steps = 128 VGPRs
  bf16x8 b[4][8];
#pragma unroll
  for (int rt = 0; rt < 4; ++rt) {
    const unsigned short* bp = zbF + (size_t)((row0w >> 5) + rt) * 4096 + hi * 256 + lo * 8;
#pragma unroll
    for (int ks = 0; ks < 8; ++ks)
      b[rt][ks] = *reinterpret_cast<const bf16x8*>(bp + ks * 512);
  }

  f32x16 kC;                            // C-operand: -MSHIFT baked into acc
#pragma unroll
  for (int r = 0; r < 16; ++r) kC[r] = -MSHIFT;

  f32x2 s[4];
#pragma unroll
  for (int rt = 0; rt < 4; ++rt) { s[rt].x = 0.f; s[rt].y = 0.f; }

  const int c0base = cc * 1024;
  const unsigned short* abase = zbF + (size_t)(c0base >> 5) * 4096 + hi * 256 + lo * 8;

  bf16x8 a[8];
#pragma unroll
  for (int ks = 0; ks < 8; ++ks)
    a[ks] = *reinterpret_cast<const bf16x8*>(abase + ks * 512);

  for (int it = 0; it < 32; ++it) {
    const int c0 = c0base + it * 32;
    const int dr = c0 - row0w;
    const bool dg = (unsigned)dr < 128u;       // tile touches diagonal?
    const int rtd = dg ? (dr >> 5) : -1;

    // half 1: row-tiles 0,1
    f32x16 acc0 = MFMA_(a[0], b[0][0], kC, 0, 0, 0);
    f32x16 acc1 = MFMA_(a[0], b[1][0], kC, 0, 0, 0);
#pragma unroll
    for (int ks = 1; ks < 8; ++ks) {
      acc0 = MFMA_(a[ks], b[0][ks], acc0, 0, 0, 0);
      acc1 = MFMA_(a[ks], b[1][ks], acc1, 0, 0, 0);
    }
    if (!dg) {
      expAcc<false>(acc0, s[0], -1, hi);
      expAcc<false>(acc1, s[1], -1, hi);
    } else {
      expAcc<true>(acc0, s[0], rtd == 0 ? lo : -1, hi);
      expAcc<true>(acc1, s[1], rtd == 1 ? lo : -1, hi);
    }

    // half 2: row-tiles 2,3
    acc0 = MFMA_(a[0], b[2][0], kC, 0, 0, 0);
    acc1 = MFMA_(a[0], b[3][0], kC, 0, 0, 0);
#pragma unroll
    for (int ks = 1; ks < 8; ++ks) {
      acc0 = MFMA_(a[ks], b[2][ks], acc0, 0, 0, 0);
      acc1 = MFMA_(a[ks], b[3][ks], acc1, 0, 0, 0);
    }

    // pipelined single-buffer reload: a[] free after the chains above; the
    // vmcnt wait lands after the exp section below.
    if (it + 1 < 32) {
      const unsigned short* ap = abase + (size_t)(it + 1) * 4096;
#pragma unroll
      for (int ks = 0; ks < 8; ++ks)
        a[ks] = *reinterpret_cast<const bf16x8*>(ap + ks * 512);
    }

    if (!dg) {
      expAcc<false>(acc0, s[2], -1, hi);
      expAcc<false>(acc1, s[3], -1, hi);
    } else {
      expAcc<true>(acc0, s[2], rtd == 2 ? lo : -1, hi);
      expAcc<true>(acc1, s[3], rtd == 3 ? lo : -1, hi);
    }
  }

  // row sums: lane-local scalar + fold hi halves, one atomic per row per chunk
#pragma unroll
  for (int rt = 0; rt < 4; ++rt) {
    float v = s[rt].x + s[rt].y;
    v += __shfl_xor(v, 32, 64);
    if (hi == 0) atomicAdd(&S[row0w + rt * 32 + lo], v);
  }

  // ---- fused finalization: last block to finish computes the loss ----
  __threadfence();                      // this block's S atomics -> device
  __syncthreads();                      // all threads fenced
  __shared__ unsigned int lastFlag;
  if (threadIdx.x == 0) {
    unsigned int old = __hip_atomic_fetch_add(cnt, 1u, __ATOMIC_ACQ_REL,
                                              __HIP_MEMORY_SCOPE_AGENT);
    lastFlag = (old == (unsigned)(MAINB - 1)) ? 1u : 0u;
  }
  __syncthreads();
  if (lastFlag) {
    __threadfence();                    // acquire: see all blocks' S updates
    const int t = threadIdx.x;          // 256 threads
    float q = 0.f;
    for (int r = t; r < NROWS; r += 256) {
      float sv = __hip_atomic_load(&S[r], __ATOMIC_RELAXED,
                                   __HIP_MEMORY_SCOPE_AGENT);
      q += LN2 * (MSHIFT + __log2f(sv));
    }
    for (int r = t; r < PREPB; r += 256)
      q -= 4.0f * Pp[r];
    __shared__ float red[256];
    red[t] = q;
    __syncthreads();
    for (int s2 = 128; s2 > 0; s2 >>= 1) {
      if (t < s2) red[t] += red[t + s2];
      __syncthreads();
    }
    if (t == 0) out[0] = red[0] / (float)NROWS;
  }
}

// ---------------------------------------------------------------------------
extern "C" void kernel_launch(void* const* d_in, const int* in_sizes, int n_in,
                              void* d_out, int out_size, void* d_ws, size_t ws_size,
                              hipStream_t stream) {
  const float* zi = (const float*)d_in[0];
  const float* zj = (const float*)d_in[1];
  unsigned short* zbF = (unsigned short*)d_ws;                     // 4 MB
  float* S  = (float*)((char*)d_ws + (size_t)NROWS * DDIM * 2);    // 64 KB
  float* Pp = S + NROWS;                                           // 8 KB
  unsigned int* cnt = (unsigned int*)(Pp + PREPB);                 // 4 B
  float* out = (float*)d_out;

  hipLaunchKernelGGL(k_prep, dim3(PREPB), dim3(256), 0, stream, zi, zj, zbF, S, Pp, cnt);
  hipLaunchKernelGGL(k_main, dim3(MAINB), dim3(256), 0, stream, zbF, S, Pp, cnt, out);
}

// Round 8
// 144.031 us; speedup vs baseline: 1.2113x; 1.2113x over previous
//
#include <hip/hip_runtime.h>

#define TEMP    0.5f
#define LOG2E   1.4426950408889634f
#define C2      (LOG2E / TEMP)        /* t = dot * C2 */
#define SQC2    1.6986436f            /* sqrt(C2): inputs pre-scaled so MFMA dot = t */
#define MSHIFT  160.0f                /* fixed base-2 softmax shift */
#define LN2     0.6931471805599453f
#define NROWS   16384
#define BHALF   8192
#define DDIM    128
#define PREPB   2048                  /* k_prep blocks = 524288/256 */
#define MAINB   512                   /* k_main blocks */

typedef __bf16 bf16x8 __attribute__((ext_vector_type(8)));
typedef float  f32x16 __attribute__((ext_vector_type(16)));
typedef float  f32x2  __attribute__((ext_vector_type(2)));

__device__ __forceinline__ float fexp2(float x) {
#if __has_builtin(__builtin_amdgcn_exp2f)
  return __builtin_amdgcn_exp2f(x);
#else
  return exp2f(x);
#endif
}

__device__ __forceinline__ unsigned short f2bf(float f) {
  unsigned int u = __float_as_uint(f);
  unsigned int r = (u + 0x7FFFu + ((u >> 16) & 1u)) >> 16;  // RNE
  return (unsigned short)r;
}

// ---------------------------------------------------------------------------
// zbF frag-major layout: for row r, k-index k:
//   g = r/32, lo = r%32, khi = k/8, j = k%8
//   short index = g*4096 + khi*256 + lo*8 + j
// A wave's frag load (fixed ks): 64 lanes read a contiguous 1KB block.
// Values are pre-scaled by SQC2, so an MFMA dot directly yields t = dot/T*log2e.
// ---------------------------------------------------------------------------

// k_prep: cast concat(z_i,z_j)*SQC2 fp32->bf16 into frag-major zbF; per-block
// partial dot(z_i,z_j) (UNscaled, exact fp32) -> Pp[block]; zero S and cnt.
__global__ void k_prep(const float* __restrict__ zi, const float* __restrict__ zj,
                       unsigned short* __restrict__ zbF,
                       float* __restrict__ S, float* __restrict__ Pp,
                       unsigned int* __restrict__ cnt) {
  const int t   = blockIdx.x * 256 + threadIdx.x;   // 0..524287 float4 groups
  const int row = t >> 5;                           // 32 float4 per 128-elt row
  const int k0  = (t & 31) * 4;
  const float* src = (row < BHALF) ? (zi + (size_t)row * DDIM)
                                   : (zj + (size_t)(row - BHALF) * DDIM);
  float4 v = *reinterpret_cast<const float4*>(src + k0);

  const int g = row >> 5, lo = row & 31, khi = k0 >> 3, j0 = k0 & 7;
  ushort4 o;
  o.x = f2bf(v.x * SQC2); o.y = f2bf(v.y * SQC2);
  o.z = f2bf(v.z * SQC2); o.w = f2bf(v.w * SQC2);
  *reinterpret_cast<ushort4*>(zbF + (size_t)g * 4096 + khi * 256 + lo * 8 + j0) = o;

  float dot = 0.f;
  if (row < BHALF) {
    float4 w = *reinterpret_cast<const float4*>(zj + (size_t)row * DDIM + k0);
    dot = fmaf(v.x, w.x, fmaf(v.y, w.y, fmaf(v.z, w.z, v.w * w.w)));
  }
#pragma unroll
  for (int m = 32; m >= 1; m >>= 1) dot += __shfl_xor(dot, m, 64);
  __shared__ float red[4];
  if ((threadIdx.x & 63) == 0) red[threadIdx.x >> 6] = dot;
  __syncthreads();
  if (threadIdx.x == 0) Pp[blockIdx.x] = red[0] + red[1] + red[2] + red[3];

  if (t < NROWS) S[t] = 0.f;
  if (t == 0) cnt[0] = 0u;              // completion counter for fused fin
}

// ---------------------------------------------------------------------------
// k_main: wave holds 128 persistent rows as MFMA *B* operand (lane-indexed in
// C/D -> scalar row sums). Streams 32-col tiles as the A operand, coalesced
// frag loads from frag-major zbF. Single-buffer pipelined reload under the
// exp section. No LDS/barriers in the hot loop.
//
// Hot loop = the r4 73.5us structure, frozen (every interleave attempt
// spilled: r1/r2/r5 WRITE_SIZE 1->19-162MB; thin-wave TLP regressed: r6).
// Deltas kept:
//  * kC = -MSHIFT C-operand (reg-neutral: replaces all-zero kZ) + SQC2
//    pre-scale  =>  exp section is exp2 + pk_add only (no pk_fma).
//  * fused finalization with RELAXED per-block signaling. r7's per-block
//    __threadfence()+ACQ_REL emitted buffer_inv per retiring block, nuking
//    L2-resident zbF for in-flight blocks (k_main 73.5->120.9us, stall
//    25%->58%). Now: per-wave s_waitcnt vmcnt(0) + relaxed add; the ONE
//    acquire fence lives in the last block only.
// ---------------------------------------------------------------------------
template <bool MASK>
__device__ __forceinline__ void expAcc(const f32x16& acc, f32x2& s, int d, int hi) {
#pragma unroll
  for (int k = 0; k < 8; ++k) {
    f32x2 e;
    e.x = fexp2(acc[2 * k]);
    e.y = fexp2(acc[2 * k + 1]);
    if (MASK) {
      const int r0 = 2 * k, r1 = 2 * k + 1;
      if (((r0 & 3) + 8 * (r0 >> 2) + 4 * hi) == d) e.x = 0.f;  // C/D reg map
      if (((r1 & 3) + 8 * (r1 >> 2) + 4 * hi) == d) e.y = 0.f;
    }
    s += e;                                                     // v_pk_add_f32
  }
}

#define MFMA_ __builtin_amdgcn_mfma_f32_32x32x16_bf16

__global__ __launch_bounds__(256, 2)
void k_main(const unsigned short* __restrict__ zbF, float* __restrict__ S,
            const float* __restrict__ Pp, unsigned int* __restrict__ cnt,
            float* __restrict__ out) {
  const int wave = threadIdx.x >> 6;
  const int lane = threadIdx.x & 63;
  const int lo = lane & 31;
  const int hi = lane >> 5;
  const int rb = blockIdx.x & 31;       // 32 row blocks of 512 rows
  const int cc = blockIdx.x >> 5;       // 16 col chunks of 1024 cols
  const int row0w = rb * 512 + wave * 128;

  // persistent row frags (B operand): 4 row-tiles x 8 k-steps = 128 VGPRs
  bf16x8 b[4][8];
#pragma unroll
  for (int rt = 0; rt < 4; ++rt) {
    const unsigned short* bp = zbF + (size_t)((row0w >> 5) + rt) * 4096 + hi * 256 + lo * 8;
#pragma unroll
    for (int ks = 0; ks < 8; ++ks)
      b[rt][ks] = *reinterpret_cast<const bf16x8*>(bp + ks * 512);
  }

  f32x16 kC;                            // C-operand: -MSHIFT baked into acc
#pragma unroll
  for (int r = 0; r < 16; ++r) kC[r] = -MSHIFT;

  f32x2 s[4];
#pragma unroll
  for (int rt = 0; rt < 4; ++rt) { s[rt].x = 0.f; s[rt].y = 0.f; }

  const int c0base = cc * 1024;
  const unsigned short* abase = zbF + (size_t)(c0base >> 5) * 4096 + hi * 256 + lo * 8;

  bf16x8 a[8];
#pragma unroll
  for (int ks = 0; ks < 8; ++ks)
    a[ks] = *reinterpret_cast<const bf16x8*>(abase + ks * 512);

  // seed anti-phase between the 2 waves/SIMD (part of the measured-best r4 build)
  if (((blockIdx.x ^ wave) & 1) != 0) __builtin_amdgcn_s_sleep(4);

  for (int it = 0; it < 32; ++it) {
    const int c0 = c0base + it * 32;
    const int dr = c0 - row0w;
    const bool dg = (unsigned)dr < 128u;       // tile touches diagonal?
    const int rtd = dg ? (dr >> 5) : -1;

    // half 1: row-tiles 0,1
    __builtin_amdgcn_s_setprio(1);
    f32x16 acc0 = MFMA_(a[0], b[0][0], kC, 0, 0, 0);
    f32x16 acc1 = MFMA_(a[0], b[1][0], kC, 0, 0, 0);
#pragma unroll
    for (int ks = 1; ks < 8; ++ks) {
      acc0 = MFMA_(a[ks], b[0][ks], acc0, 0, 0, 0);
      acc1 = MFMA_(a[ks], b[1][ks], acc1, 0, 0, 0);
    }
    __builtin_amdgcn_s_setprio(0);
    if (!dg) {
      expAcc<false>(acc0, s[0], -1, hi);
      expAcc<false>(acc1, s[1], -1, hi);
    } else {
      expAcc<true>(acc0, s[0], rtd == 0 ? lo : -1, hi);
      expAcc<true>(acc1, s[1], rtd == 1 ? lo : -1, hi);
    }

    // half 2: row-tiles 2,3
    __builtin_amdgcn_s_setprio(1);
    acc0 = MFMA_(a[0], b[2][0], kC, 0, 0, 0);
    acc1 = MFMA_(a[0], b[3][0], kC, 0, 0, 0);
#pragma unroll
    for (int ks = 1; ks < 8; ++ks) {
      acc0 = MFMA_(a[ks], b[2][ks], acc0, 0, 0, 0);
      acc1 = MFMA_(a[ks], b[3][ks], acc1, 0, 0, 0);
    }
    __builtin_amdgcn_s_setprio(0);

    // pipelined single-buffer reload: a[] free after the chains above; the
    // vmcnt wait lands after the exp section below.
    if (it + 1 < 32) {
      const unsigned short* ap = abase + (size_t)(it + 1) * 4096;
#pragma unroll
      for (int ks = 0; ks < 8; ++ks)
        a[ks] = *reinterpret_cast<const bf16x8*>(ap + ks * 512);
    }

    if (!dg) {
      expAcc<false>(acc0, s[2], -1, hi);
      expAcc<false>(acc1, s[3], -1, hi);
    } else {
      expAcc<true>(acc0, s[2], rtd == 2 ? lo : -1, hi);
      expAcc<true>(acc1, s[3], rtd == 3 ? lo : -1, hi);
    }
  }

  // row sums: lane-local scalar + fold hi halves, one atomic per row per chunk
#pragma unroll
  for (int rt = 0; rt < 4; ++rt) {
    float v = s[rt].x + s[rt].y;
    v += __shfl_xor(v, 32, 64);
    if (hi == 0) atomicAdd(&S[row0w + rt * 32 + lo], v);
  }

  // ---- fused finalization, cache-benign signaling ----
  // Drain this wave's S atomics (no cache maintenance!), then one relaxed
  // counter add per block. Acquire (buffer_inv) happens ONCE, in the last
  // block, after all compute everywhere is done.
  asm volatile("s_waitcnt vmcnt(0)" ::: "memory");
  __syncthreads();                      // all 4 waves drained
  __shared__ unsigned int lastFlag;
  if (threadIdx.x == 0) {
    unsigned int old = __hip_atomic_fetch_add(cnt, 1u, __ATOMIC_RELAXED,
                                              __HIP_MEMORY_SCOPE_AGENT);
    lastFlag = (old == (unsigned)(MAINB - 1)) ? 1u : 0u;
  }
  __syncthreads();
  if (lastFlag) {
    __threadfence();                    // single acquire: see all S updates
    const int t = threadIdx.x;          // 256 threads
    float q = 0.f;
    for (int r = t; r < NROWS; r += 256) {
      float sv = __hip_atomic_load(&S[r], __ATOMIC_RELAXED,
                                   __HIP_MEMORY_SCOPE_AGENT);
      q += LN2 * (MSHIFT + __log2f(sv));
    }
    for (int r = t; r < PREPB; r += 256)
      q -= 4.0f * Pp[r];
    __shared__ float red[256];
    red[t] = q;
    __syncthreads();
    for (int s2 = 128; s2 > 0; s2 >>= 1) {
      if (t < s2) red[t] += red[t + s2];
      __syncthreads();
    }
    if (t == 0) out[0] = red[0] / (float)NROWS;
  }
}

// ---------------------------------------------------------------------------
extern "C" void kernel_launch(void* const* d_in, const int* in_sizes, int n_in,
                              void* d_out, int out_size, void* d_ws, size_t ws_size,
                              hipStream_t stream) {
  const float* zi = (const float*)d_in[0];
  const float* zj = (const float*)d_in[1];
  unsigned short* zbF = (unsigned short*)d_ws;                     // 4 MB
  float* S  = (float*)((char*)d_ws + (size_t)NROWS * DDIM * 2);    // 64 KB
  float* Pp = S + NROWS;                                           // 8 KB
  unsigned int* cnt = (unsigned int*)(Pp + PREPB);                 // 4 B
  float* out = (float*)d_out;

  hipLaunchKernelGGL(k_prep, dim3(PREPB), dim3(256), 0, stream, zi, zj, zbF, S, Pp, cnt);
  hipLaunchKernelGGL(k_main, dim3(MAINB), dim3(256), 0, stream, zbF, S, Pp, cnt, out);
}

// Round 9
// 139.891 us; speedup vs baseline: 1.2472x; 1.0296x over previous
//
#include <hip/hip_runtime.h>

#define TEMP    0.5f
#define LOG2E   1.4426950408889634f
#define C2      (LOG2E / TEMP)        /* t = dot * C2 */
#define SQC2    1.6986436f            /* sqrt(C2): inputs pre-scaled so MFMA dot = t */
#define MSHIFT  160.0f                /* fixed base-2 softmax shift */
#define LN2     0.6931471805599453f
#define NROWS   16384
#define BHALF   8192
#define DDIM    128
#define PREPB   2048                  /* k_prep blocks = 524288/256 */

typedef __bf16 bf16x8 __attribute__((ext_vector_type(8)));
typedef float  f32x16 __attribute__((ext_vector_type(16)));
typedef float  f32x2  __attribute__((ext_vector_type(2)));

__device__ __forceinline__ float fexp2(float x) {
#if __has_builtin(__builtin_amdgcn_exp2f)
  return __builtin_amdgcn_exp2f(x);
#else
  return exp2f(x);
#endif
}

__device__ __forceinline__ unsigned short f2bf(float f) {
  unsigned int u = __float_as_uint(f);
  unsigned int r = (u + 0x7FFFu + ((u >> 16) & 1u)) >> 16;  // RNE
  return (unsigned short)r;
}

// ---------------------------------------------------------------------------
// zbF frag-major layout: for row r, k-index k:
//   g = r/32, lo = r%32, khi = k/8, j = k%8
//   short index = g*4096 + khi*256 + lo*8 + j
// A wave's frag load (fixed ks): 64 lanes read a contiguous 1KB block.
// Values are pre-scaled by SQC2, so an MFMA dot directly yields t = dot/T*log2e.
// ---------------------------------------------------------------------------

// k_prep: cast concat(z_i,z_j)*SQC2 fp32->bf16 into frag-major zbF; per-block
// partial dot(z_i,z_j) (UNscaled, exact fp32) -> Pp[block]; zero S.
__global__ void k_prep(const float* __restrict__ zi, const float* __restrict__ zj,
                       unsigned short* __restrict__ zbF,
                       float* __restrict__ S, float* __restrict__ Pp) {
  const int t   = blockIdx.x * 256 + threadIdx.x;   // 0..524287 float4 groups
  const int row = t >> 5;                           // 32 float4 per 128-elt row
  const int k0  = (t & 31) * 4;
  const float* src = (row < BHALF) ? (zi + (size_t)row * DDIM)
                                   : (zj + (size_t)(row - BHALF) * DDIM);
  float4 v = *reinterpret_cast<const float4*>(src + k0);

  const int g = row >> 5, lo = row & 31, khi = k0 >> 3, j0 = k0 & 7;
  ushort4 o;
  o.x = f2bf(v.x * SQC2); o.y = f2bf(v.y * SQC2);
  o.z = f2bf(v.z * SQC2); o.w = f2bf(v.w * SQC2);
  *reinterpret_cast<ushort4*>(zbF + (size_t)g * 4096 + khi * 256 + lo * 8 + j0) = o;

  float dot = 0.f;
  if (row < BHALF) {
    float4 w = *reinterpret_cast<const float4*>(zj + (size_t)row * DDIM + k0);
    dot = fmaf(v.x, w.x, fmaf(v.y, w.y, fmaf(v.z, w.z, v.w * w.w)));
  }
#pragma unroll
  for (int m = 32; m >= 1; m >>= 1) dot += __shfl_xor(dot, m, 64);
  __shared__ float red[4];
  if ((threadIdx.x & 63) == 0) red[threadIdx.x >> 6] = dot;
  __syncthreads();
  if (threadIdx.x == 0) Pp[blockIdx.x] = red[0] + red[1] + red[2] + red[3];

  if (t < NROWS) S[t] = 0.f;
}

// ---------------------------------------------------------------------------
// k_main: wave holds 128 persistent rows as MFMA *B* operand (lane-indexed in
// C/D -> scalar row sums). Streams 32-col tiles as the A operand, coalesced
// frag loads from frag-major zbF. Single-buffer pipelined reload under the
// exp section. No LDS, no barriers. Structure = r4's measured-best 73.5us.
//
// Round-9: SINGLE delta vs r4 = kC (-MSHIFT C-operand, inputs pre-scaled by
// sqrt(C2)) so the exp section is exp2 + pk_add only — isolating kC from the
// fused-epilogue regression of r7/r8 (epilogue removed; 3 dispatches again).
// FROZEN lessons: no exp/MFMA source interleave (r1/r2/r5 spilled, WRITE
// 1->19-162MB: unified VGPR+AGPR file is ~full); no thin waves (r6 +17us);
// no per-block device fences (r7 buffer_inv storm +47us).
// ---------------------------------------------------------------------------
template <bool MASK>
__device__ __forceinline__ void expAcc(const f32x16& acc, f32x2& s, int d, int hi) {
#pragma unroll
  for (int k = 0; k < 8; ++k) {
    f32x2 e;
    e.x = fexp2(acc[2 * k]);
    e.y = fexp2(acc[2 * k + 1]);
    if (MASK) {
      const int r0 = 2 * k, r1 = 2 * k + 1;
      if (((r0 & 3) + 8 * (r0 >> 2) + 4 * hi) == d) e.x = 0.f;  // C/D reg map
      if (((r1 & 3) + 8 * (r1 >> 2) + 4 * hi) == d) e.y = 0.f;
    }
    s += e;                                                     // v_pk_add_f32
  }
}

#define MFMA_ __builtin_amdgcn_mfma_f32_32x32x16_bf16

__global__ __launch_bounds__(256, 2)
void k_main(const unsigned short* __restrict__ zbF, float* __restrict__ S) {
  const int wave = threadIdx.x >> 6;
  const int lane = threadIdx.x & 63;
  const int lo = lane & 31;
  const int hi = lane >> 5;
  const int rb = blockIdx.x & 31;       // 32 row blocks of 512 rows
  const int cc = blockIdx.x >> 5;       // 16 col chunks of 1024 cols
  const int row0w = rb * 512 + wave * 128;

  // persistent row frags (B operand): 4 row-tiles x 8 k-steps
  bf16x8 b[4][8];
#pragma unroll
  for (int rt = 0; rt < 4; ++rt) {
    const unsigned short* bp = zbF + (size_t)((row0w >> 5) + rt) * 4096 + hi * 256 + lo * 8;
#pragma unroll
    for (int ks = 0; ks < 8; ++ks)
      b[rt][ks] = *reinterpret_cast<const bf16x8*>(bp + ks * 512);
  }

  f32x16 kC;                            // C-operand: -MSHIFT baked into acc
#pragma unroll
  for (int r = 0; r < 16; ++r) kC[r] = -MSHIFT;

  f32x2 s[4];
#pragma unroll
  for (int rt = 0; rt < 4; ++rt) { s[rt].x = 0.f; s[rt].y = 0.f; }

  const int c0base = cc * 1024;
  const unsigned short* abase = zbF + (size_t)(c0base >> 5) * 4096 + hi * 256 + lo * 8;

  bf16x8 a[8];
#pragma unroll
  for (int ks = 0; ks < 8; ++ks)
    a[ks] = *reinterpret_cast<const bf16x8*>(abase + ks * 512);

  // seed anti-phase between the 2 waves/SIMD (part of the measured-best r4 build)
  if (((blockIdx.x ^ wave) & 1) != 0) __builtin_amdgcn_s_sleep(4);

  for (int it = 0; it < 32; ++it) {
    const int c0 = c0base + it * 32;
    const int dr = c0 - row0w;
    const bool dg = (unsigned)dr < 128u;       // tile touches diagonal?
    const int rtd = dg ? (dr >> 5) : -1;

    // half 1: row-tiles 0,1
    __builtin_amdgcn_s_setprio(1);
    f32x16 acc0 = MFMA_(a[0], b[0][0], kC, 0, 0, 0);
    f32x16 acc1 = MFMA_(a[0], b[1][0], kC, 0, 0, 0);
#pragma unroll
    for (int ks = 1; ks < 8; ++ks) {
      acc0 = MFMA_(a[ks], b[0][ks], acc0, 0, 0, 0);
      acc1 = MFMA_(a[ks], b[1][ks], acc1, 0, 0, 0);
    }
    __builtin_amdgcn_s_setprio(0);
    if (!dg) {
      expAcc<false>(acc0, s[0], -1, hi);
      expAcc<false>(acc1, s[1], -1, hi);
    } else {
      expAcc<true>(acc0, s[0], rtd == 0 ? lo : -1, hi);
      expAcc<true>(acc1, s[1], rtd == 1 ? lo : -1, hi);
    }

    // half 2: row-tiles 2,3
    __builtin_amdgcn_s_setprio(1);
    acc0 = MFMA_(a[0], b[2][0], kC, 0, 0, 0);
    acc1 = MFMA_(a[0], b[3][0], kC, 0, 0, 0);
#pragma unroll
    for (int ks = 1; ks < 8; ++ks) {
      acc0 = MFMA_(a[ks], b[2][ks], acc0, 0, 0, 0);
      acc1 = MFMA_(a[ks], b[3][ks], acc1, 0, 0, 0);
    }
    __builtin_amdgcn_s_setprio(0);

    // pipelined single-buffer reload: a[] free after the chains above; the
    // vmcnt wait lands after the exp section below.
    if (it + 1 < 32) {
      const unsigned short* ap = abase + (size_t)(it + 1) * 4096;
#pragma unroll
      for (int ks = 0; ks < 8; ++ks)
        a[ks] = *reinterpret_cast<const bf16x8*>(ap + ks * 512);
    }

    if (!dg) {
      expAcc<false>(acc0, s[2], -1, hi);
      expAcc<false>(acc1, s[3], -1, hi);
    } else {
      expAcc<true>(acc0, s[2], rtd == 2 ? lo : -1, hi);
      expAcc<true>(acc1, s[3], rtd == 3 ? lo : -1, hi);
    }
  }

  // row sums: lane-local scalar + fold hi halves, one atomic per row per chunk
#pragma unroll
  for (int rt = 0; rt < 4; ++rt) {
    float v = s[rt].x + s[rt].y;
    v += __shfl_xor(v, 32, 64);
    if (hi == 0) atomicAdd(&S[row0w + rt * 32 + lo], v);
  }
}

// ---------------------------------------------------------------------------
// k_fin: out = ( LN2 * sum_k (M + log2 S_k)  -  4 * sum Pp ) / N
// Linear -> single fused block reduction (1024 threads).
// ---------------------------------------------------------------------------
__global__ void k_fin(const float* __restrict__ S, const float* __restrict__ Pp,
                      float* __restrict__ out) {
  const int t = threadIdx.x;            // 1024 threads
  float q = 0.f;
  for (int r = t; r < NROWS; r += 1024)
    q += LN2 * (MSHIFT + __log2f(S[r]));
  for (int r = t; r < PREPB; r += 1024)
    q -= 4.0f * Pp[r];
  __shared__ float red[1024];
  red[t] = q;
  __syncthreads();
  for (int s2 = 512; s2 > 0; s2 >>= 1) {
    if (t < s2) red[t] += red[t + s2];
    __syncthreads();
  }
  if (t == 0) out[0] = red[0] / (float)NROWS;
}

// ---------------------------------------------------------------------------
extern "C" void kernel_launch(void* const* d_in, const int* in_sizes, int n_in,
                              void* d_out, int out_size, void* d_ws, size_t ws_size,
                              hipStream_t stream) {
  const float* zi = (const float*)d_in[0];
  const float* zj = (const float*)d_in[1];
  unsigned short* zbF = (unsigned short*)d_ws;                     // 4 MB
  float* S  = (float*)((char*)d_ws + (size_t)NROWS * DDIM * 2);    // 64 KB
  float* Pp = S + NROWS;                                           // 8 KB
  float* out = (float*)d_out;

  hipLaunchKernelGGL(k_prep, dim3(PREPB), dim3(256), 0, stream, zi, zj, zbF, S, Pp);
  hipLaunchKernelGGL(k_main, dim3(512),  dim3(256), 0, stream, zbF, S);
  hipLaunchKernelGGL(k_fin,  dim3(1),    dim3(1024), 0, stream, S, Pp, out);
}